// Round 9
// baseline (162.161 us; speedup 1.0000x reference)
//
#include <hip/hip_runtime.h>
#include <math.h>

typedef float f32x2 __attribute__((ext_vector_type(2)));

#define NCH 96      // B*C = 32*3
#define HH 512
#define WW 512
#define OH 502      // valid output rows/cols (512 - 10)
#define STRIP 32    // output rows per block (last strip = 22, even)
#define NSTRIP 16
#define NT 256      // threads per block, 2 columns each

struct Win { float w[11]; };

__device__ __forceinline__ f32x2 pkfma(f32x2 a, f32x2 b, f32x2 c) {
    return __builtin_elementwise_fma(a, b, c);
}
__device__ __forceinline__ f32x2 pkfmas(f32x2 a, float s, f32x2 c) {
    f32x2 sv = {s, s};
    return __builtin_elementwise_fma(a, sv, c);
}
__device__ __forceinline__ f32x2 pkmuls(f32x2 a, float s) {
    f32x2 sv = {s, s};
    return a * sv;
}

// packed SSIM for two pixels: mu1,mu2,ms,mp hold (pixelA, pixelB)
__device__ __forceinline__ float ssim_px2(f32x2 mu1, f32x2 mu2, f32x2 ms, f32x2 mp) {
    const f32x2 C1v = {1e-4f, 1e-4f};   // (0.01)^2
    const f32x2 C2v = {9e-4f, 9e-4f};   // (0.03)^2
    const f32x2 two = {2.f, 2.f};
    f32x2 mu12  = mu1 * mu2;
    f32x2 musum = pkfma(mu1, mu1, mu2 * mu2);
    f32x2 num = pkfma(two, mp - mu12, C2v) * pkfma(two, mu12, C1v);
    f32x2 den = ((ms - musum) + C2v) * (musum + C1v); // > 0 always
    float ra = __builtin_amdgcn_rcpf(den.x);
    float rb = __builtin_amdgcn_rcpf(den.y);
    return fmaf(num.x, ra, num.y * rb);
}

// packed 11-tap horizontal blur chain (taps T0..T10, scalar weights w0..w10)
#define HB(T0,T1,T2,T3,T4,T5,T6,T7,T8,T9,T10) \
  pkfmas(T10, w10, pkfmas(T9, w9, pkfmas(T8, w8, pkfmas(T7, w7, \
  pkfmas(T6, w6, pkfmas(T5, w5, pkfmas(T4, w4, pkfmas(T3, w3, \
  pkfmas(T2, w2, pkfmas(T1, w1, pkmuls(T0, w0)))))))))))

__global__ __launch_bounds__(NT, 6)
void ssim_main(const float* __restrict__ X, const float* __restrict__ Y,
               float* __restrict__ partial, Win win) {
    // Single-buffered (16.2 KB): write/read separated by two barriers per iter.
    // M = (mu1_e, mu2_e, mu1_o, mu2_o); S = (ms_e, mp_e, ms_o, mp_o)
    __shared__ float4 Mb[2][256];   // [row01][colpair]
    __shared__ float4 Sb[2][256];
    __shared__ float red[4];

    const int b     = blockIdx.x;
    const int ch    = b >> 4;         // / NSTRIP
    const int strip = b & 15;
    const int r0    = strip * STRIP;
    const int rows  = min(STRIP, OH - r0);   // 32 or 22 (even)
    const int t     = threadIdx.x;

    const float w0 = win.w[0], w1 = win.w[1], w2 = win.w[2], w3 = win.w[3];
    const float w4 = win.w[4], w5 = win.w[5], w6 = win.w[6], w7 = win.w[7];
    const float w8 = win.w[8], w9 = win.w[9], w10 = win.w[10];
    const f32x2 h2 = {0.5f, 0.5f};

    const size_t choff = (size_t)ch * (HH * WW);
    const float* xcol = X + choff + 2 * t;   // column-pair base
    const float* ycol = Y + choff + 2 * t;

    // 10-slot shift ring of NORMALIZED (even,odd) packed values.
    f32x2 xs[10], ys[10];
    #pragma unroll
    for (int i = 0; i < 10; ++i) {
        f32x2 xv = *(const f32x2*)(xcol + (size_t)(r0 + i) * WW);
        f32x2 yv = *(const f32x2*)(ycol + (size_t)(r0 + i) * WW);
        xs[i] = pkfma(xv, h2, h2);
        ys[i] = pkfma(yv, h2, h2);
    }
    // held raw rows r0+10, r0+11
    f32x2 hx1 = *(const f32x2*)(xcol + (size_t)(r0 + 10) * WW);
    f32x2 hy1 = *(const f32x2*)(ycol + (size_t)(r0 + 10) * WW);
    f32x2 hx2 = *(const f32x2*)(xcol + (size_t)(r0 + 11) * WW);
    f32x2 hy2 = *(const f32x2*)(ycol + (size_t)(r0 + 11) * WW);

    float acc = 0.f;

    for (int r = 0; r < rows; r += 2) {
        // normalize held rows (consume prefetch); s,p on the fly
        f32x2 n1x = pkfma(hx1, h2, h2), n1y = pkfma(hy1, h2, h2);
        f32x2 n2x = pkfma(hx2, h2, h2), n2y = pkfma(hy2, h2, h2);
        f32x2 n1s = pkfma(n1y, n1y, n1x * n1x), n1p = n1x * n1y;
        f32x2 n2s = pkfma(n2y, n2y, n2x * n2x), n2p = n2x * n2y;

        // vblur row A = r   : w[k] over ring[0..9] (rows r..r+9) + w10*n1
        //       row B = r+1 : w[k-1] over ring[1..9] + w9*n1 + w10*n2
        f32x2 uAx = pkmuls(n1x, w10), uAy = pkmuls(n1y, w10);
        f32x2 uAs = pkmuls(n1s, w10), uAp = pkmuls(n1p, w10);
        f32x2 uBx = pkfmas(n1x, w9, pkmuls(n2x, w10));
        f32x2 uBy = pkfmas(n1y, w9, pkmuls(n2y, w10));
        f32x2 uBs = pkfmas(n1s, w9, pkmuls(n2s, w10));
        f32x2 uBp = pkfmas(n1p, w9, pkmuls(n2p, w10));
        #pragma unroll
        for (int k = 0; k < 10; ++k) {
            const float wk = win.w[k];
            f32x2 qx = xs[k], qy = ys[k];
            f32x2 qs = pkfma(qy, qy, qx * qx), qp = qx * qy;   // shared by both rows
            uAx = pkfmas(qx, wk, uAx); uAy = pkfmas(qy, wk, uAy);
            uAs = pkfmas(qs, wk, uAs); uAp = pkfmas(qp, wk, uAp);
            if (k >= 1) {
                const float wk1 = win.w[k - 1];
                uBx = pkfmas(qx, wk1, uBx); uBy = pkfmas(qy, wk1, uBy);
                uBs = pkfmas(qs, wk1, uBs); uBp = pkfmas(qp, wk1, uBp);
            }
        }

        // shift ring by 2; append normalized held rows
        #pragma unroll
        for (int k = 0; k < 8; ++k) { xs[k] = xs[k + 2]; ys[k] = ys[k + 2]; }
        xs[8] = n1x; ys[8] = n1y; xs[9] = n2x; ys[9] = n2y;

        // BARRIER A: all threads finished reading previous iter's LDS contents
        __syncthreads();

        Mb[0][t] = make_float4(uAx.x, uAy.x, uAx.y, uAy.y);
        Sb[0][t] = make_float4(uAs.x, uAp.x, uAs.y, uAp.y);
        Mb[1][t] = make_float4(uBx.x, uBy.x, uBx.y, uBy.y);
        Sb[1][t] = make_float4(uBs.x, uBp.x, uBs.y, uBp.y);

        // BARRIER B: writes visible
        __syncthreads();

        // issue prefetch AFTER the barrier: loads stay in flight under hblur +
        // next iteration's vblur instead of being drained by barrier vmcnt(0).
        {
            const int g1 = min(r0 + r + 12, HH - 1);
            const int g2 = min(r0 + r + 13, HH - 1);
            hx1 = *(const f32x2*)(xcol + (size_t)g1 * WW);
            hy1 = *(const f32x2*)(ycol + (size_t)g1 * WW);
            hx2 = *(const f32x2*)(xcol + (size_t)g2 * WW);
            hy2 = *(const f32x2*)(ycol + (size_t)g2 * WW);
        }

        // horizontal blur + ssim for output cols 2t, 2t+1 of both rows
        if (t <= 250) {
            #pragma unroll
            for (int rr = 0; rr < 2; ++rr) {
                const float4* Mp = Mb[rr];
                const float4* Sp = Sb[rr];
                float4 m0 = Mp[t],     m1 = Mp[t + 1], m2 = Mp[t + 2];
                float4 m3 = Mp[t + 3], m4 = Mp[t + 4], m5 = Mp[t + 5];
                float4 s0 = Sp[t],     s1 = Sp[t + 1], s2 = Sp[t + 2];
                float4 s3 = Sp[t + 3], s4 = Sp[t + 4], s5 = Sp[t + 5];
                f32x2 e0m = {m0.x, m0.y}, o0m = {m0.z, m0.w};
                f32x2 e1m = {m1.x, m1.y}, o1m = {m1.z, m1.w};
                f32x2 e2m = {m2.x, m2.y}, o2m = {m2.z, m2.w};
                f32x2 e3m = {m3.x, m3.y}, o3m = {m3.z, m3.w};
                f32x2 e4m = {m4.x, m4.y}, o4m = {m4.z, m4.w};
                f32x2 e5m = {m5.x, m5.y}, o5m = {m5.z, m5.w};
                f32x2 e0s = {s0.x, s0.y}, o0s = {s0.z, s0.w};
                f32x2 e1s = {s1.x, s1.y}, o1s = {s1.z, s1.w};
                f32x2 e2s = {s2.x, s2.y}, o2s = {s2.z, s2.w};
                f32x2 e3s = {s3.x, s3.y}, o3s = {s3.z, s3.w};
                f32x2 e4s = {s4.x, s4.y}, o4s = {s4.z, s4.w};
                f32x2 e5s = {s5.x, s5.y}, o5s = {s5.z, s5.w};

                f32x2 Am = HB(e0m,o0m,e1m,o1m,e2m,o2m,e3m,o3m,e4m,o4m,e5m);
                f32x2 As = HB(e0s,o0s,e1s,o1s,e2s,o2s,e3s,o3s,e4s,o4s,e5s);
                f32x2 Bm = HB(o0m,e1m,o1m,e2m,o2m,e3m,o3m,e4m,o4m,e5m,o5m);
                f32x2 Bs = HB(o0s,e1s,o1s,e2s,o2s,e3s,o3s,e4s,o4s,e5s,o5s);

                f32x2 mu1 = {Am.x, Bm.x}, mu2 = {Am.y, Bm.y};
                f32x2 msv = {As.x, Bs.x}, mpv = {As.y, Bs.y};
                acc += ssim_px2(mu1, mu2, msv, mpv);
            }
        }
    }

    // block reduction -> one partial per block (no atomics: deterministic)
    #pragma unroll
    for (int m = 1; m < 64; m <<= 1) acc += __shfl_xor(acc, m, 64);
    __syncthreads();
    if ((t & 63) == 0) red[t >> 6] = acc;
    __syncthreads();
    if (t == 0) partial[b] = (red[0] + red[1]) + (red[2] + red[3]);
}

__global__ __launch_bounds__(128)
void ssim_final(const float* __restrict__ partial, float* __restrict__ out) {
    const int t = threadIdx.x;  // 128 threads
    float v = 0.f;
    if (t < NCH) {
        float s = 0.f;
        #pragma unroll
        for (int i = 0; i < NSTRIP; ++i) s += partial[t * NSTRIP + i];
        s *= (1.f / (502.f * 502.f));   // per-channel spatial mean
        v = fmaxf(s, 0.f);              // relu (nonnegative_ssim)
    }
    #pragma unroll
    for (int m = 1; m < 64; m <<= 1) v += __shfl_xor(v, m, 64);
    __shared__ float r2[2];
    if ((t & 63) == 0) r2[t >> 6] = v;
    __syncthreads();
    if (t == 0) out[0] = 1.f - (r2[0] + r2[1]) * (1.f / (float)NCH);
}

extern "C" void kernel_launch(void* const* d_in, const int* in_sizes, int n_in,
                              void* d_out, int out_size, void* d_ws, size_t ws_size,
                              hipStream_t stream) {
    const float* X = (const float*)d_in[0];
    const float* Y = (const float*)d_in[1];
    float* out = (float*)d_out;
    float* partial = (float*)d_ws;   // NCH*NSTRIP = 1536 floats

    Win win;
    double g[11], sum = 0.0;
    for (int i = 0; i < 11; ++i) {
        double c = (double)(i - 5);
        g[i] = exp(-(c * c) / (2.0 * 1.5 * 1.5));
        sum += g[i];
    }
    for (int i = 0; i < 11; ++i) win.w[i] = (float)(g[i] / sum);

    ssim_main<<<NCH * NSTRIP, NT, 0, stream>>>(X, Y, partial, win);
    ssim_final<<<1, 128, 0, stream>>>(partial, out);
}

// Round 10
// 158.909 us; speedup vs baseline: 1.0205x; 1.0205x over previous
//
#include <hip/hip_runtime.h>
#include <math.h>

typedef float f32x2 __attribute__((ext_vector_type(2)));

#define NCH 96      // B*C = 32*3
#define HH 512
#define WW 512
#define OH 502      // valid output rows/cols (512 - 10)
#define STRIP 32    // output rows per block (last strip = 22, even)
#define NSTRIP 16
#define NT 256      // threads per block, 2 columns each

struct Win { float w[11]; };

__device__ __forceinline__ f32x2 pkfma(f32x2 a, f32x2 b, f32x2 c) {
    return __builtin_elementwise_fma(a, b, c);
}
__device__ __forceinline__ f32x2 pkfmas(f32x2 a, float s, f32x2 c) {
    f32x2 sv = {s, s};
    return __builtin_elementwise_fma(a, sv, c);
}
__device__ __forceinline__ f32x2 pkmuls(f32x2 a, float s) {
    f32x2 sv = {s, s};
    return a * sv;
}

// packed SSIM for two pixels: mu1,mu2,ms,mp hold (pixelA, pixelB)
__device__ __forceinline__ float ssim_px2(f32x2 mu1, f32x2 mu2, f32x2 ms, f32x2 mp) {
    const f32x2 C1v = {1e-4f, 1e-4f};   // (0.01)^2
    const f32x2 C2v = {9e-4f, 9e-4f};   // (0.03)^2
    const f32x2 two = {2.f, 2.f};
    f32x2 mu12  = mu1 * mu2;
    f32x2 musum = pkfma(mu1, mu1, mu2 * mu2);
    f32x2 num = pkfma(two, mp - mu12, C2v) * pkfma(two, mu12, C1v);
    f32x2 den = ((ms - musum) + C2v) * (musum + C1v); // > 0 always
    float ra = __builtin_amdgcn_rcpf(den.x);
    float rb = __builtin_amdgcn_rcpf(den.y);
    return fmaf(num.x, ra, num.y * rb);
}

// packed 11-tap horizontal blur chain (taps T0..T10, scalar weights w0..w10)
#define HB(T0,T1,T2,T3,T4,T5,T6,T7,T8,T9,T10) \
  pkfmas(T10, w10, pkfmas(T9, w9, pkfmas(T8, w8, pkfmas(T7, w7, \
  pkfmas(T6, w6, pkfmas(T5, w5, pkfmas(T4, w4, pkfmas(T3, w3, \
  pkfmas(T2, w2, pkfmas(T1, w1, pkmuls(T0, w0)))))))))))

__global__ __launch_bounds__(NT, 4)
void ssim_main(const float* __restrict__ X, const float* __restrict__ Y,
               float* __restrict__ partial, Win win) {
    // Single buffer (16.4 KB): write/read separated by the two barriers.
    // M = (mu1_e, mu2_e, mu1_o, mu2_o); S = (ms_e, mp_e, ms_o, mp_o)
    __shared__ float4 Mb[2][256];   // [row01][colpair]
    __shared__ float4 Sb[2][256];
    __shared__ float red[4];

    const int b     = blockIdx.x;
    const int ch    = b >> 4;         // / NSTRIP
    const int strip = b & 15;
    const int r0    = strip * STRIP;
    const int rows  = min(STRIP, OH - r0);   // 32 or 22 (even)
    const int t     = threadIdx.x;
    const int ti    = min(t, 250);    // clamped index for unguarded LDS reads

    const float w0 = win.w[0], w1 = win.w[1], w2 = win.w[2], w3 = win.w[3];
    const float w4 = win.w[4], w5 = win.w[5], w6 = win.w[6], w7 = win.w[7];
    const float w8 = win.w[8], w9 = win.w[9], w10 = win.w[10];
    const f32x2 h2 = {0.5f, 0.5f};

    const size_t choff = (size_t)ch * (HH * WW);
    const float* xcol = X + choff + 2 * t;   // column-pair base
    const float* ycol = Y + choff + 2 * t;

    // 10-slot shift ring of NORMALIZED (even,odd) packed values.
    f32x2 xs[10], ys[10];
    #pragma unroll
    for (int i = 0; i < 10; ++i) {
        f32x2 xv = *(const f32x2*)(xcol + (size_t)(r0 + i) * WW);
        f32x2 yv = *(const f32x2*)(ycol + (size_t)(r0 + i) * WW);
        xs[i] = pkfma(xv, h2, h2);
        ys[i] = pkfma(yv, h2, h2);
    }
    // held raw rows: h1 = rows r+10,r+11; h2r = rows r+12,r+13; h3 = prefetch
    f32x2 h1xa = *(const f32x2*)(xcol + (size_t)(r0 + 10) * WW);
    f32x2 h1ya = *(const f32x2*)(ycol + (size_t)(r0 + 10) * WW);
    f32x2 h1xb = *(const f32x2*)(xcol + (size_t)(r0 + 11) * WW);
    f32x2 h1yb = *(const f32x2*)(ycol + (size_t)(r0 + 11) * WW);
    f32x2 h2xa = *(const f32x2*)(xcol + (size_t)min(r0 + 12, HH - 1) * WW);
    f32x2 h2ya = *(const f32x2*)(ycol + (size_t)min(r0 + 12, HH - 1) * WW);
    f32x2 h2xb = *(const f32x2*)(xcol + (size_t)min(r0 + 13, HH - 1) * WW);
    f32x2 h2yb = *(const f32x2*)(ycol + (size_t)min(r0 + 13, HH - 1) * WW);
    f32x2 h3xa, h3ya, h3xb, h3yb;

    // u registers: vblur of the next pair to be written (starts as rows 0,1)
    f32x2 uAx, uAy, uAs, uAp, uBx, uBy, uBs, uBp;
    {
        f32x2 n1x = pkfma(h1xa, h2, h2), n1y = pkfma(h1ya, h2, h2);
        f32x2 n2x = pkfma(h1xb, h2, h2), n2y = pkfma(h1yb, h2, h2);
        f32x2 s1 = pkfma(n1y, n1y, n1x * n1x), p1 = n1x * n1y;
        f32x2 s2 = pkfma(n2y, n2y, n2x * n2x), p2 = n2x * n2y;
        uAx = pkmuls(n1x, w10); uAy = pkmuls(n1y, w10);
        uAs = pkmuls(s1, w10);  uAp = pkmuls(p1, w10);
        uBx = pkfmas(n1x, w9, pkmuls(n2x, w10));
        uBy = pkfmas(n1y, w9, pkmuls(n2y, w10));
        uBs = pkfmas(s1, w9, pkmuls(s2, w10));
        uBp = pkfmas(p1, w9, pkmuls(p2, w10));
        #pragma unroll
        for (int k = 0; k < 10; ++k) {
            const float wk = win.w[k];
            f32x2 qx = xs[k], qy = ys[k];
            f32x2 qs = pkfma(qy, qy, qx * qx), qp = qx * qy;
            uAx = pkfmas(qx, wk, uAx); uAy = pkfmas(qy, wk, uAy);
            uAs = pkfmas(qs, wk, uAs); uAp = pkfmas(qp, wk, uAp);
            if (k >= 1) {
                const float wk1 = win.w[k - 1];
                uBx = pkfmas(qx, wk1, uBx); uBy = pkfmas(qy, wk1, uBy);
                uBs = pkfmas(qs, wk1, uBs); uBp = pkfmas(qp, wk1, uBp);
            }
        }
    }

    float acc = 0.f;

    for (int r = 0; r < rows; r += 2) {
        __syncthreads();   // A: all threads done reading previous LDS contents
        Mb[0][t] = make_float4(uAx.x, uAy.x, uAx.y, uAy.y);
        Sb[0][t] = make_float4(uAs.x, uAp.x, uAs.y, uAp.y);
        Mb[1][t] = make_float4(uBx.x, uBy.x, uBx.y, uBy.y);
        Sb[1][t] = make_float4(uBs.x, uBp.x, uBs.y, uBp.y);
        __syncthreads();   // B: writes visible

        // issue row-0 hblur reads early: latency hides under the vblur below
        float4 m0 = Mb[0][ti],     m1 = Mb[0][ti + 1], m2 = Mb[0][ti + 2];
        float4 m3 = Mb[0][ti + 3], m4 = Mb[0][ti + 4], m5 = Mb[0][ti + 5];
        float4 s0 = Sb[0][ti],     s1r = Sb[0][ti + 1], s2r = Sb[0][ti + 2];
        float4 s3r = Sb[0][ti + 3], s4r = Sb[0][ti + 4], s5r = Sb[0][ti + 5];

        if (r + 2 < rows) {   // uniform: prepare u = vblur(r+2, r+3)
            // prefetch h3 = raw rows r0+r+14, r0+r+15 (distance 2)
            const int g1 = min(r0 + r + 14, HH - 1);
            const int g2 = min(r0 + r + 15, HH - 1);
            h3xa = *(const f32x2*)(xcol + (size_t)g1 * WW);
            h3ya = *(const f32x2*)(ycol + (size_t)g1 * WW);
            h3xb = *(const f32x2*)(xcol + (size_t)g2 * WW);
            h3yb = *(const f32x2*)(ycol + (size_t)g2 * WW);

            // normalize held rows r+10..r+13
            f32x2 n1x = pkfma(h1xa, h2, h2), n1y = pkfma(h1ya, h2, h2);
            f32x2 n2x = pkfma(h1xb, h2, h2), n2y = pkfma(h1yb, h2, h2);
            f32x2 n3x = pkfma(h2xa, h2, h2), n3y = pkfma(h2ya, h2, h2);
            f32x2 n4x = pkfma(h2xb, h2, h2), n4y = pkfma(h2yb, h2, h2);
            f32x2 sv1 = pkfma(n1y, n1y, n1x * n1x), pv1 = n1x * n1y;
            f32x2 sv2 = pkfma(n2y, n2y, n2x * n2x), pv2 = n2x * n2y;
            f32x2 sv3 = pkfma(n3y, n3y, n3x * n3x), pv3 = n3x * n3y;
            f32x2 sv4 = pkfma(n4y, n4y, n4x * n4x), pv4 = n4x * n4y;

            // row r+2: w[s-2]*ring[s] (s=2..9) + w8*n1 + w9*n2 + w10*n3
            uAx = pkfmas(n1x, w8, pkfmas(n2x, w9, pkmuls(n3x, w10)));
            uAy = pkfmas(n1y, w8, pkfmas(n2y, w9, pkmuls(n3y, w10)));
            uAs = pkfmas(sv1, w8, pkfmas(sv2, w9, pkmuls(sv3, w10)));
            uAp = pkfmas(pv1, w8, pkfmas(pv2, w9, pkmuls(pv3, w10)));
            // row r+3: w[s-3]*ring[s] (s=3..9) + w7*n1 + w8*n2 + w9*n3 + w10*n4
            uBx = pkfmas(n1x, w7, pkfmas(n2x, w8, pkfmas(n3x, w9, pkmuls(n4x, w10))));
            uBy = pkfmas(n1y, w7, pkfmas(n2y, w8, pkfmas(n3y, w9, pkmuls(n4y, w10))));
            uBs = pkfmas(sv1, w7, pkfmas(sv2, w8, pkfmas(sv3, w9, pkmuls(sv4, w10))));
            uBp = pkfmas(pv1, w7, pkfmas(pv2, w8, pkfmas(pv3, w9, pkmuls(pv4, w10))));
            #pragma unroll
            for (int k = 2; k <= 9; ++k) {
                const float wkA = win.w[k - 2];
                f32x2 qx = xs[k], qy = ys[k];
                f32x2 qs = pkfma(qy, qy, qx * qx), qp = qx * qy;
                uAx = pkfmas(qx, wkA, uAx); uAy = pkfmas(qy, wkA, uAy);
                uAs = pkfmas(qs, wkA, uAs); uAp = pkfmas(qp, wkA, uAp);
                if (k >= 3) {
                    const float wkB = win.w[k - 3];
                    uBx = pkfmas(qx, wkB, uBx); uBy = pkfmas(qy, wkB, uBy);
                    uBs = pkfmas(qs, wkB, uBs); uBp = pkfmas(qp, wkB, uBp);
                }
            }
            // shift ring by 2; append normalized rows r+10, r+11
            #pragma unroll
            for (int k = 0; k < 8; ++k) { xs[k] = xs[k + 2]; ys[k] = ys[k + 2]; }
            xs[8] = n1x; ys[8] = n1y; xs[9] = n2x; ys[9] = n2y;
            // rotate held registers
            h1xa = h2xa; h1ya = h2ya; h1xb = h2xb; h1yb = h2yb;
            h2xa = h3xa; h2ya = h3ya; h2xb = h3xb; h2yb = h3yb;
        }

        // hblur + ssim, row r
        if (t <= 250) {
            f32x2 e0m = {m0.x, m0.y}, o0m = {m0.z, m0.w};
            f32x2 e1m = {m1.x, m1.y}, o1m = {m1.z, m1.w};
            f32x2 e2m = {m2.x, m2.y}, o2m = {m2.z, m2.w};
            f32x2 e3m = {m3.x, m3.y}, o3m = {m3.z, m3.w};
            f32x2 e4m = {m4.x, m4.y}, o4m = {m4.z, m4.w};
            f32x2 e5m = {m5.x, m5.y}, o5m = {m5.z, m5.w};
            f32x2 e0s = {s0.x, s0.y}, o0s = {s0.z, s0.w};
            f32x2 e1s = {s1r.x, s1r.y}, o1s = {s1r.z, s1r.w};
            f32x2 e2s = {s2r.x, s2r.y}, o2s = {s2r.z, s2r.w};
            f32x2 e3s = {s3r.x, s3r.y}, o3s = {s3r.z, s3r.w};
            f32x2 e4s = {s4r.x, s4r.y}, o4s = {s4r.z, s4r.w};
            f32x2 e5s = {s5r.x, s5r.y}, o5s = {s5r.z, s5r.w};
            f32x2 Am = HB(e0m,o0m,e1m,o1m,e2m,o2m,e3m,o3m,e4m,o4m,e5m);
            f32x2 As = HB(e0s,o0s,e1s,o1s,e2s,o2s,e3s,o3s,e4s,o4s,e5s);
            f32x2 Bm = HB(o0m,e1m,o1m,e2m,o2m,e3m,o3m,e4m,o4m,e5m,o5m);
            f32x2 Bs = HB(o0s,e1s,o1s,e2s,o2s,e3s,o3s,e4s,o4s,e5s,o5s);
            f32x2 mu1 = {Am.x, Bm.x}, mu2 = {Am.y, Bm.y};
            f32x2 msv = {As.x, Bs.x}, mpv = {As.y, Bs.y};
            acc += ssim_px2(mu1, mu2, msv, mpv);
        }

        // row r+1 reads + hblur
        {
            float4 n0 = Mb[1][ti],     n1f = Mb[1][ti + 1], n2f = Mb[1][ti + 2];
            float4 n3f = Mb[1][ti + 3], n4f = Mb[1][ti + 4], n5f = Mb[1][ti + 5];
            float4 t0 = Sb[1][ti],     t1f = Sb[1][ti + 1], t2f = Sb[1][ti + 2];
            float4 t3f = Sb[1][ti + 3], t4f = Sb[1][ti + 4], t5f = Sb[1][ti + 5];
            if (t <= 250) {
                f32x2 e0m = {n0.x, n0.y}, o0m = {n0.z, n0.w};
                f32x2 e1m = {n1f.x, n1f.y}, o1m = {n1f.z, n1f.w};
                f32x2 e2m = {n2f.x, n2f.y}, o2m = {n2f.z, n2f.w};
                f32x2 e3m = {n3f.x, n3f.y}, o3m = {n3f.z, n3f.w};
                f32x2 e4m = {n4f.x, n4f.y}, o4m = {n4f.z, n4f.w};
                f32x2 e5m = {n5f.x, n5f.y}, o5m = {n5f.z, n5f.w};
                f32x2 e0s = {t0.x, t0.y}, o0s = {t0.z, t0.w};
                f32x2 e1s = {t1f.x, t1f.y}, o1s = {t1f.z, t1f.w};
                f32x2 e2s = {t2f.x, t2f.y}, o2s = {t2f.z, t2f.w};
                f32x2 e3s = {t3f.x, t3f.y}, o3s = {t3f.z, t3f.w};
                f32x2 e4s = {t4f.x, t4f.y}, o4s = {t4f.z, t4f.w};
                f32x2 e5s = {t5f.x, t5f.y}, o5s = {t5f.z, t5f.w};
                f32x2 Am = HB(e0m,o0m,e1m,o1m,e2m,o2m,e3m,o3m,e4m,o4m,e5m);
                f32x2 As = HB(e0s,o0s,e1s,o1s,e2s,o2s,e3s,o3s,e4s,o4s,e5s);
                f32x2 Bm = HB(o0m,e1m,o1m,e2m,o2m,e3m,o3m,e4m,o4m,e5m,o5m);
                f32x2 Bs = HB(o0s,e1s,o1s,e2s,o2s,e3s,o3s,e4s,o4s,e5s,o5s);
                f32x2 mu1 = {Am.x, Bm.x}, mu2 = {Am.y, Bm.y};
                f32x2 msv = {As.x, Bs.x}, mpv = {As.y, Bs.y};
                acc += ssim_px2(mu1, mu2, msv, mpv);
            }
        }
    }

    // block reduction -> one partial per block (no atomics: deterministic)
    #pragma unroll
    for (int m = 1; m < 64; m <<= 1) acc += __shfl_xor(acc, m, 64);
    __syncthreads();
    if ((t & 63) == 0) red[t >> 6] = acc;
    __syncthreads();
    if (t == 0) partial[b] = (red[0] + red[1]) + (red[2] + red[3]);
}

__global__ __launch_bounds__(128)
void ssim_final(const float* __restrict__ partial, float* __restrict__ out) {
    const int t = threadIdx.x;  // 128 threads
    float v = 0.f;
    if (t < NCH) {
        float s = 0.f;
        #pragma unroll
        for (int i = 0; i < NSTRIP; ++i) s += partial[t * NSTRIP + i];
        s *= (1.f / (502.f * 502.f));   // per-channel spatial mean
        v = fmaxf(s, 0.f);              // relu (nonnegative_ssim)
    }
    #pragma unroll
    for (int m = 1; m < 64; m <<= 1) v += __shfl_xor(v, m, 64);
    __shared__ float r2[2];
    if ((t & 63) == 0) r2[t >> 6] = v;
    __syncthreads();
    if (t == 0) out[0] = 1.f - (r2[0] + r2[1]) * (1.f / (float)NCH);
}

extern "C" void kernel_launch(void* const* d_in, const int* in_sizes, int n_in,
                              void* d_out, int out_size, void* d_ws, size_t ws_size,
                              hipStream_t stream) {
    const float* X = (const float*)d_in[0];
    const float* Y = (const float*)d_in[1];
    float* out = (float*)d_out;
    float* partial = (float*)d_ws;   // NCH*NSTRIP = 1536 floats

    Win win;
    double g[11], sum = 0.0;
    for (int i = 0; i < 11; ++i) {
        double c = (double)(i - 5);
        g[i] = exp(-(c * c) / (2.0 * 1.5 * 1.5));
        sum += g[i];
    }
    for (int i = 0; i < 11; ++i) win.w[i] = (float)(g[i] / sum);

    ssim_main<<<NCH * NSTRIP, NT, 0, stream>>>(X, Y, partial, win);
    ssim_final<<<1, 128, 0, stream>>>(partial, out);
}

// Round 11
// 77.775 us; speedup vs baseline: 2.0850x; 2.0432x over previous
//
#include <hip/hip_runtime.h>
#include <math.h>

typedef float f32x2 __attribute__((ext_vector_type(2)));

#define NCH 96      // B*C = 32*3
#define HH 512
#define WW 512
#define OH 502      // valid output rows/cols (512 - 10)
#define STRIP 32    // output rows per block (last strip = 22, even)
#define NSTRIP 16
#define NT 256      // threads per block, 2 columns each

struct Win { float w[11]; };

__device__ __forceinline__ f32x2 pkfma(f32x2 a, f32x2 b, f32x2 c) {
    return __builtin_elementwise_fma(a, b, c);
}
__device__ __forceinline__ f32x2 pkfmas(f32x2 a, float s, f32x2 c) {
    f32x2 sv = {s, s};
    return __builtin_elementwise_fma(a, sv, c);
}
__device__ __forceinline__ f32x2 pkmuls(f32x2 a, float s) {
    f32x2 sv = {s, s};
    return a * sv;
}

// packed SSIM for two pixels: mu1,mu2,ms,mp hold (pixelA, pixelB)
__device__ __forceinline__ float ssim_px2(f32x2 mu1, f32x2 mu2, f32x2 ms, f32x2 mp) {
    const f32x2 C1v = {1e-4f, 1e-4f};   // (0.01)^2
    const f32x2 C2v = {9e-4f, 9e-4f};   // (0.03)^2
    const f32x2 two = {2.f, 2.f};
    f32x2 mu12  = mu1 * mu2;
    f32x2 musum = pkfma(mu1, mu1, mu2 * mu2);
    f32x2 num = pkfma(two, mp - mu12, C2v) * pkfma(two, mu12, C1v);
    f32x2 den = ((ms - musum) + C2v) * (musum + C1v); // > 0 always
    float ra = __builtin_amdgcn_rcpf(den.x);
    float rb = __builtin_amdgcn_rcpf(den.y);
    return fmaf(num.x, ra, num.y * rb);
}

// packed 11-tap horizontal blur chain (taps T0..T10, scalar weights w0..w10)
#define HB(T0,T1,T2,T3,T4,T5,T6,T7,T8,T9,T10) \
  pkfmas(T10, w10, pkfmas(T9, w9, pkfmas(T8, w8, pkfmas(T7, w7, \
  pkfmas(T6, w6, pkfmas(T5, w5, pkfmas(T4, w4, pkfmas(T3, w3, \
  pkfmas(T2, w2, pkfmas(T1, w1, pkmuls(T0, w0)))))))))))

__global__ __launch_bounds__(NT, 4)
void ssim_main(const float* __restrict__ X, const float* __restrict__ Y,
               float* __restrict__ partial, Win win) {
    // SINGLE buffer (16.6 KB -> 6 blocks/CU residency, grid-capped):
    // write/read separated by two barriers per iteration.
    // M = (mu1_e, mu2_e, mu1_o, mu2_o); S = (ms_e, mp_e, ms_o, mp_o)
    __shared__ float4 Mb[2][256];   // [row01][colpair]
    __shared__ float4 Sb[2][256];
    __shared__ float red[4];

    const int b     = blockIdx.x;
    const int ch    = b >> 4;         // / NSTRIP
    const int strip = b & 15;
    const int r0    = strip * STRIP;
    const int rows  = min(STRIP, OH - r0);   // 32 or 22 (even)
    const int t     = threadIdx.x;

    const float w0 = win.w[0], w1 = win.w[1], w2 = win.w[2], w3 = win.w[3];
    const float w4 = win.w[4], w5 = win.w[5], w6 = win.w[6], w7 = win.w[7];
    const float w8 = win.w[8], w9 = win.w[9], w10 = win.w[10];
    const f32x2 h2 = {0.5f, 0.5f};

    const size_t choff = (size_t)ch * (HH * WW);
    const float* xcol = X + choff + 2 * t;   // column-pair base
    const float* ycol = Y + choff + 2 * t;

    // 10-slot shift ring of NORMALIZED (even,odd) packed values.
    f32x2 xs[10], ys[10];
    #pragma unroll
    for (int i = 0; i < 10; ++i) {
        f32x2 xv = *(const f32x2*)(xcol + (size_t)(r0 + i) * WW);
        f32x2 yv = *(const f32x2*)(ycol + (size_t)(r0 + i) * WW);
        xs[i] = pkfma(xv, h2, h2);
        ys[i] = pkfma(yv, h2, h2);
    }
    // held raw rows r0+10, r0+11
    f32x2 hx1 = *(const f32x2*)(xcol + (size_t)(r0 + 10) * WW);
    f32x2 hy1 = *(const f32x2*)(ycol + (size_t)(r0 + 10) * WW);
    f32x2 hx2 = *(const f32x2*)(xcol + (size_t)(r0 + 11) * WW);
    f32x2 hy2 = *(const f32x2*)(ycol + (size_t)(r0 + 11) * WW);

    float acc = 0.f;

    for (int r = 0; r < rows; r += 2) {
        // normalize held rows (consume prefetch); s,p on the fly
        f32x2 n1x = pkfma(hx1, h2, h2), n1y = pkfma(hy1, h2, h2);
        f32x2 n2x = pkfma(hx2, h2, h2), n2y = pkfma(hy2, h2, h2);
        f32x2 n1s = pkfma(n1y, n1y, n1x * n1x), n1p = n1x * n1y;
        f32x2 n2s = pkfma(n2y, n2y, n2x * n2x), n2p = n2x * n2y;

        // vblur row A = r   : w[k] over ring[0..9] (rows r..r+9) + w10*n1
        //       row B = r+1 : w[k-1] over ring[1..9] + w9*n1 + w10*n2
        f32x2 uAx = pkmuls(n1x, w10), uAy = pkmuls(n1y, w10);
        f32x2 uAs = pkmuls(n1s, w10), uAp = pkmuls(n1p, w10);
        f32x2 uBx = pkfmas(n1x, w9, pkmuls(n2x, w10));
        f32x2 uBy = pkfmas(n1y, w9, pkmuls(n2y, w10));
        f32x2 uBs = pkfmas(n1s, w9, pkmuls(n2s, w10));
        f32x2 uBp = pkfmas(n1p, w9, pkmuls(n2p, w10));
        #pragma unroll
        for (int k = 0; k < 10; ++k) {
            const float wk = win.w[k];
            f32x2 qx = xs[k], qy = ys[k];
            f32x2 qs = pkfma(qy, qy, qx * qx), qp = qx * qy;   // shared by both rows
            uAx = pkfmas(qx, wk, uAx); uAy = pkfmas(qy, wk, uAy);
            uAs = pkfmas(qs, wk, uAs); uAp = pkfmas(qp, wk, uAp);
            if (k >= 1) {
                const float wk1 = win.w[k - 1];
                uBx = pkfmas(qx, wk1, uBx); uBy = pkfmas(qy, wk1, uBy);
                uBs = pkfmas(qs, wk1, uBs); uBp = pkfmas(qp, wk1, uBp);
            }
        }

        // shift ring by 2; append normalized held rows
        #pragma unroll
        for (int k = 0; k < 8; ++k) { xs[k] = xs[k + 2]; ys[k] = ys[k + 2]; }
        xs[8] = n1x; ys[8] = n1y; xs[9] = n2x; ys[9] = n2y;

        // BARRIER A: all threads done reading previous iteration's LDS data
        __syncthreads();

        Mb[0][t] = make_float4(uAx.x, uAy.x, uAx.y, uAy.y);
        Sb[0][t] = make_float4(uAs.x, uAp.x, uAs.y, uAp.y);
        Mb[1][t] = make_float4(uBx.x, uBy.x, uBx.y, uBy.y);
        Sb[1][t] = make_float4(uBs.x, uBp.x, uBs.y, uBp.y);

        // BARRIER B: writes visible
        __syncthreads();

        // prefetch AFTER the barrier: loads land during the hblur region,
        // before the NEXT iteration's barrier A drains vmcnt.
        {
            const int g1 = min(r0 + r + 12, HH - 1);
            const int g2 = min(r0 + r + 13, HH - 1);
            hx1 = *(const f32x2*)(xcol + (size_t)g1 * WW);
            hy1 = *(const f32x2*)(ycol + (size_t)g1 * WW);
            hx2 = *(const f32x2*)(xcol + (size_t)g2 * WW);
            hy2 = *(const f32x2*)(ycol + (size_t)g2 * WW);
        }

        // horizontal blur + ssim for output cols 2t, 2t+1 of both rows
        if (t <= 250) {
            #pragma unroll
            for (int rr = 0; rr < 2; ++rr) {
                const float4* Mp = Mb[rr];
                const float4* Sp = Sb[rr];
                float4 m0 = Mp[t],     m1 = Mp[t + 1], m2 = Mp[t + 2];
                float4 m3 = Mp[t + 3], m4 = Mp[t + 4], m5 = Mp[t + 5];
                float4 s0 = Sp[t],     s1 = Sp[t + 1], s2 = Sp[t + 2];
                float4 s3 = Sp[t + 3], s4 = Sp[t + 4], s5 = Sp[t + 5];
                f32x2 e0m = {m0.x, m0.y}, o0m = {m0.z, m0.w};
                f32x2 e1m = {m1.x, m1.y}, o1m = {m1.z, m1.w};
                f32x2 e2m = {m2.x, m2.y}, o2m = {m2.z, m2.w};
                f32x2 e3m = {m3.x, m3.y}, o3m = {m3.z, m3.w};
                f32x2 e4m = {m4.x, m4.y}, o4m = {m4.z, m4.w};
                f32x2 e5m = {m5.x, m5.y}, o5m = {m5.z, m5.w};
                f32x2 e0s = {s0.x, s0.y}, o0s = {s0.z, s0.w};
                f32x2 e1s = {s1.x, s1.y}, o1s = {s1.z, s1.w};
                f32x2 e2s = {s2.x, s2.y}, o2s = {s2.z, s2.w};
                f32x2 e3s = {s3.x, s3.y}, o3s = {s3.z, s3.w};
                f32x2 e4s = {s4.x, s4.y}, o4s = {s4.z, s4.w};
                f32x2 e5s = {s5.x, s5.y}, o5s = {s5.z, s5.w};

                f32x2 Am = HB(e0m,o0m,e1m,o1m,e2m,o2m,e3m,o3m,e4m,o4m,e5m);
                f32x2 As = HB(e0s,o0s,e1s,o1s,e2s,o2s,e3s,o3s,e4s,o4s,e5s);
                f32x2 Bm = HB(o0m,e1m,o1m,e2m,o2m,e3m,o3m,e4m,o4m,e5m,o5m);
                f32x2 Bs = HB(o0s,e1s,o1s,e2s,o2s,e3s,o3s,e4s,o4s,e5s,o5s);

                f32x2 mu1 = {Am.x, Bm.x}, mu2 = {Am.y, Bm.y};
                f32x2 msv = {As.x, Bs.x}, mpv = {As.y, Bs.y};
                acc += ssim_px2(mu1, mu2, msv, mpv);
            }
        }
    }

    // block reduction -> one partial per block (no atomics: deterministic)
    #pragma unroll
    for (int m = 1; m < 64; m <<= 1) acc += __shfl_xor(acc, m, 64);
    __syncthreads();
    if ((t & 63) == 0) red[t >> 6] = acc;
    __syncthreads();
    if (t == 0) partial[b] = (red[0] + red[1]) + (red[2] + red[3]);
}

__global__ __launch_bounds__(128)
void ssim_final(const float* __restrict__ partial, float* __restrict__ out) {
    const int t = threadIdx.x;  // 128 threads
    float v = 0.f;
    if (t < NCH) {
        float s = 0.f;
        #pragma unroll
        for (int i = 0; i < NSTRIP; ++i) s += partial[t * NSTRIP + i];
        s *= (1.f / (502.f * 502.f));   // per-channel spatial mean
        v = fmaxf(s, 0.f);              // relu (nonnegative_ssim)
    }
    #pragma unroll
    for (int m = 1; m < 64; m <<= 1) v += __shfl_xor(v, m, 64);
    __shared__ float r2[2];
    if ((t & 63) == 0) r2[t >> 6] = v;
    __syncthreads();
    if (t == 0) out[0] = 1.f - (r2[0] + r2[1]) * (1.f / (float)NCH);
}

extern "C" void kernel_launch(void* const* d_in, const int* in_sizes, int n_in,
                              void* d_out, int out_size, void* d_ws, size_t ws_size,
                              hipStream_t stream) {
    const float* X = (const float*)d_in[0];
    const float* Y = (const float*)d_in[1];
    float* out = (float*)d_out;
    float* partial = (float*)d_ws;   // NCH*NSTRIP = 1536 floats

    Win win;
    double g[11], sum = 0.0;
    for (int i = 0; i < 11; ++i) {
        double c = (double)(i - 5);
        g[i] = exp(-(c * c) / (2.0 * 1.5 * 1.5));
        sum += g[i];
    }
    for (int i = 0; i < 11; ++i) win.w[i] = (float)(g[i] / sum);

    ssim_main<<<NCH * NSTRIP, NT, 0, stream>>>(X, Y, partial, win);
    ssim_final<<<1, 128, 0, stream>>>(partial, out);
}